// Round 19
// baseline (200.093 us; speedup 1.0000x reference)
//
#include <hip/hip_runtime.h>

#define NX 1024
#define NT 64
#define NBATCH 16
#define BPB 64           // blocks per batch chain (16 cells each)
#define NBLK (NBATCH * BPB)   // 1024 blocks = 256 CUs x 4 single-wave blocks
#define DXC 0.02f
#define BIGF 1.0e6f

typedef __attribute__((ext_vector_type(8))) short bf16x8;
typedef __attribute__((ext_vector_type(4))) float f32x4;
typedef __attribute__((ext_vector_type(2))) float f32x2;
typedef unsigned long long u64t;

// round-to-nearest-even f32 -> bf16
__device__ __forceinline__ unsigned short f2bf(float x) {
    unsigned u = __builtin_bit_cast(unsigned, x);
    u += 0x7FFFu + ((u >> 16) & 1u);
    return (unsigned short)(u >> 16);
}
__device__ __forceinline__ float bf2f(unsigned short h) {
    return __builtin_bit_cast(float, (unsigned)h << 16);
}
__device__ __forceinline__ unsigned cvt_pk_bf16(float lo, float hi) {
    unsigned r;
    asm("v_cvt_pk_bf16_f32 %0, %1, %2" : "=v"(r) : "v"(lo), "v"(hi));
    return r;
}
__device__ __forceinline__ float hw_exp2(float v) {
    float e;
    asm("v_exp_f32 %0, %1" : "=v"(e) : "v"(v));
    return e;
}

// 2-wide tanh-form GELU, native vector C (r17 lesson: no hand VOP3P asm).
__device__ __forceinline__ f32x2 pk_gelu(f32x2 x) {
    f32x2 x2 = x * x;
    f32x2 v  = x * (x2 * 0.1029456f + 2.3022654f);
    f32x2 rc;
    rc.x = __builtin_amdgcn_rcpf(hw_exp2(v.x) + 1.0f);
    rc.y = __builtin_amdgcn_rcpf(hw_exp2(v.y) + 1.0f);
    return x - x * rc;
}

// SYSTEM-scope relaxed (L3 coherence point; no cache inv/wb) — cross-XCD safe.
__device__ __forceinline__ u64t sys_load_u64(const u64t* p) {
    return __hip_atomic_load(p, __ATOMIC_RELAXED, __HIP_MEMORY_SCOPE_SYSTEM);
}
__device__ __forceinline__ void sys_store_u64(u64t* p, u64t v) {
    __hip_atomic_store(p, v, __ATOMIC_RELAXED, __HIP_MEMORY_SCOPE_SYSTEM);
}

// XOR-swizzled [R][64] bf16 LDS layout.
__device__ __forceinline__ int swz(int row, int k) {
    return (row << 6) + ((((k >> 3) ^ row) & 7) << 3) + (k & 7);
}

// wave-internal phase fence: order DS producer->consumer (insurance on top of
// per-wave in-order LDS) and pin the scheduler (rule #18).
__device__ __forceinline__ void wave_fence() {
    asm volatile("s_waitcnt lgkmcnt(0)" ::: "memory");
    __builtin_amdgcn_sched_barrier(0);
}

__global__ void __launch_bounds__(64, 1) nfv_kernel(
    const float* __restrict__ grid, const float* __restrict__ dtp,
    const float* __restrict__ W0, const float* __restrict__ b0,
    const float* __restrict__ W1, const float* __restrict__ b1,
    const float* __restrict__ W2, const float* __restrict__ b2,
    const float* __restrict__ W3, const float* __restrict__ b3,
    float* __restrict__ outp, u64t* __restrict__ halo)
{
    __shared__ float st_s[80];      // state strip, global [c0-32, c0+48)
    __shared__ __align__(16) unsigned short feat_s[16 * 64];
    __shared__ __align__(16) unsigned short actA[16 * 64];
    __shared__ __align__(16) unsigned short actB[16 * 64];

    const int lane = threadIdx.x;         // single wave: 0..63
    const int bid  = blockIdx.x;
    const int b    = bid >> 6;            // batch
    const int bb   = bid & 63;            // block within chain
    const int c0   = bb * 16;
    const float dtv = dtp[b];
    const float r   = dtv / DXC;
    const float b3v = b3[0];

    const float* grow = grid + (size_t)b * (NT * NX);
    float*       orow = outp + (size_t)b * (NT * NX);

    const int l15 = lane & 15;
    const int kb0 = lane >> 4;            // 0..3
    const int row0 = kb0 << 2;            // C rows 0,4,8,12 (+j)
    const int k0  = kb0 * 8;

    // ---- prologue: weight fragments for ALL 4 channel tiles (registers) ----
    bf16x8 w0f[4], w1fa[4], w1fb[4], w2fa[4], w2fb[4];
    float bias0[4], bias1[4], bias2[4], w3c[4];
    #pragma unroll
    for (int tt = 0; tt < 4; ++tt) {
        const int colt = tt * 16 + l15;
        #pragma unroll
        for (int i = 0; i < 8; ++i) {
            int k = k0 + i;
            float wv;
            if (k < 7)       wv = W0[colt * 22 + k] - 2.0f * W0[colt * 22 + 7 + k];
            else if (k < 14) wv = W0[colt * 22 + (k - 7)] - 2.0f * W0[colt * 22 + k];
            else if (k < 22) wv = W0[colt * 22 + k];
            else             wv = 0.0f;
            w0f[tt][i]  = (short)f2bf(wv);
            w1fa[tt][i] = (short)f2bf(W1[colt * 64 + k0 + i]);
            w1fb[tt][i] = (short)f2bf(W1[colt * 64 + k0 + 32 + i]);
            w2fa[tt][i] = (short)f2bf(W2[colt * 64 + k0 + i]);
            w2fb[tt][i] = (short)f2bf(W2[colt * 64 + k0 + 32 + i]);
        }
        float bb0 = b0[colt];
        #pragma unroll
        for (int k = 7; k < 14; ++k) bb0 += W0[colt * 22 + k];
        bias0[tt] = bb0;
        bias1[tt] = b1[colt];
        bias2[tt] = b2[colt];
        w3c[tt]   = W3[colt];
    }

    // A-frag read offsets (shared by all 4 tiles; arow = l15)
    const int aoffA = (l15 << 6) + ((((kb0    ) ^ l15) & 7) << 3);
    const int aoffB = (l15 << 6) + ((((kb0 + 4) ^ l15) & 7) << 3);
    const bf16x8* const prF  = (const bf16x8*)(const void*)&feat_s[aoffA];
    const bf16x8* const prA0 = (const bf16x8*)(const void*)&actA[aoffA];
    const bf16x8* const prA1 = (const bf16x8*)(const void*)&actA[aoffB];
    const bf16x8* const prB0 = (const bf16x8*)(const void*)&actB[aoffA];
    const bf16x8* const prB1 = (const bf16x8*)(const void*)&actB[aoffB];

    // act store offsets: 4 tiles x 4 rows, same offset in actA and actB
    int soff[16];
    #pragma unroll
    for (int tt = 0; tt < 4; ++tt)
        #pragma unroll
        for (int j = 0; j < 4; ++j)
            soff[tt * 4 + j] = swz(row0 + j, tt * 16 + l15);

    // feature-phase constants: pass0 slot kb0, pass1 slot kb0+4 (if <7)
    int fc0 = l15 + 29 + kb0;
    int fc1 = l15 + 29 + kb0 + 4;
    if (bb == 0)   { if (fc0 < 32) fc0 = 32; if (fc1 < 32) fc1 = 32; }
    if (bb == BPB - 1) { if (fc0 > 47) fc0 = 47; if (fc1 > 47) fc1 = 47; }
    const bool fact1 = (kb0 < 3);
    const int f0a = swz(l15, kb0),     f0b = swz(l15, 7 + kb0),  f0c = swz(l15, 14 + kb0);
    const int f1a = swz(l15, kb0 + 4), f1b = swz(l15, 11 + kb0), f1c = swz(l15, 18 + kb0);

    // halo-poll constants (all 64 lanes)
    int hg = (lane < 32) ? (c0 - 32 + lane) : (c0 - 16 + lane);
    hg = hg < 0 ? 0 : (hg > NX - 1 ? NX - 1 : hg);
    const u64t* const hbase = &halo[(size_t)(b * BPB + (hg >> 4)) * 64 + (hg & 15)];
    const int hdst = (lane < 32) ? lane : lane + 16;

    // update lanes: l15==0 (lanes 0,16,32,48) own rows row0..row0+3
    const bool upd = (l15 == 0);
    u64t* const hpub = &halo[(size_t)bid * 64 + row0];
    float st_reg[4];
    #pragma unroll
    for (int j = 0; j < 4; ++j) st_reg[j] = grow[c0 + row0 + j];  // row 0 state

    // ---- prologue LDS init ----
    #pragma unroll
    for (int i = 0; i < 8; ++i) ((unsigned*)feat_s)[lane + 64 * i] = 0;
    if (lane < 16) {
        orow[c0 + lane] = grow[c0 + lane];          // t = 0 output
        feat_s[swz(lane, 21)] = f2bf(dtv);          // dt slot, constant
    }
    {
        int ga = c0 - 32 + lane;
        ga = ga < 0 ? 0 : (ga > NX - 1 ? NX - 1 : ga);
        st_s[lane] = grow[ga];
        if (lane < 16) {
            int gb = c0 + 32 + lane;
            gb = gb > NX - 1 ? NX - 1 : gb;
            st_s[64 + lane] = grow[gb];
        }
    }
    wave_fence();

    for (int t = 1; t < NT; ++t) {
        // ---- poll halo of row t-1 (fused data+tag word per lane) ----
        if (t >= 2) {
            const unsigned need = (unsigned)(t - 1);
            const u64t* src = hbase + (size_t)(((t - 1) & 3) * 16);
            u64t u;
            do { u = sys_load_u64(src); } while ((unsigned)(u >> 32) < need);
            st_s[hdst] = __builtin_bit_cast(float, (unsigned)u);
            wave_fence();
        }

        // ---- ballots + features (2 passes: slots kb0, kb0+4) ----
        {
            bool q0 = st_s[lane + 1] > st_s[lane];               // pairs 0..63
            bool q1 = (lane < 15) && (st_s[65 + lane] > st_s[64 + lane]);
            u64t m0 = __ballot(q0);
            u64t m1 = __ballot(q1);

            #pragma unroll
            for (int pass = 0; pass < 2; ++pass) {
                if (pass == 1 && !fact1) break;
                const int c = pass ? fc1 : fc0;
                float dL = BIGF, dR = BIGF;
                u64t sello = m0 & (((u64t)1 << c) - 1);
                if (sello) dL = (float)(c - (63 - __builtin_clzll(sello))) - 0.5f;
                u64t r0 = m0 >> c;
                if (r0)      dR = (float)__builtin_ctzll(r0) + 0.5f;
                else if (m1) dR = (float)(64 - c + __builtin_ctzll(m1)) + 0.5f;
                float d = fminf(dL, dR);
                float prox = hw_exp2(d * -0.5770780f);   // exp(-0.4 d)
                float sv = st_s[c];
                unsigned short shi = f2bf(sv);
                unsigned short slo = f2bf(sv - bf2f(shi));
                feat_s[pass ? f1a : f0a] = shi;
                feat_s[pass ? f1b : f0b] = slo;
                feat_s[pass ? f1c : f0c] = f2bf(prox);
            }
        }
        wave_fence();

        // ---- L0: 1 shared A-frag read, 4 MFMAs (one per channel tile) ----
        {
            bf16x8 aF = *prF;
            f32x4 c4[4];
            #pragma unroll
            for (int tt = 0; tt < 4; ++tt) {
                c4[tt] = (f32x4){bias0[tt], bias0[tt], bias0[tt], bias0[tt]};
                c4[tt] = __builtin_amdgcn_mfma_f32_16x16x32_bf16(aF, w0f[tt], c4[tt], 0, 0, 0);
            }
            #pragma unroll
            for (int tt = 0; tt < 4; ++tt) {
                f32x2 g01 = pk_gelu((f32x2){c4[tt][0], c4[tt][1]});
                f32x2 g23 = pk_gelu((f32x2){c4[tt][2], c4[tt][3]});
                unsigned u01 = cvt_pk_bf16(g01.x, g01.y);
                unsigned u23 = cvt_pk_bf16(g23.x, g23.y);
                actA[soff[tt * 4 + 0]] = (unsigned short)u01;
                actA[soff[tt * 4 + 1]] = (unsigned short)(u01 >> 16);
                actA[soff[tt * 4 + 2]] = (unsigned short)u23;
                actA[soff[tt * 4 + 3]] = (unsigned short)(u23 >> 16);
            }
        }
        wave_fence();

        // ---- L1: 2 shared A-frag reads, 8 MFMAs ----
        {
            bf16x8 a0 = *prA0, a1 = *prA1;
            f32x4 c4[4];
            #pragma unroll
            for (int tt = 0; tt < 4; ++tt) {
                c4[tt] = (f32x4){bias1[tt], bias1[tt], bias1[tt], bias1[tt]};
                c4[tt] = __builtin_amdgcn_mfma_f32_16x16x32_bf16(a0, w1fa[tt], c4[tt], 0, 0, 0);
                c4[tt] = __builtin_amdgcn_mfma_f32_16x16x32_bf16(a1, w1fb[tt], c4[tt], 0, 0, 0);
            }
            #pragma unroll
            for (int tt = 0; tt < 4; ++tt) {
                f32x2 g01 = pk_gelu((f32x2){c4[tt][0], c4[tt][1]});
                f32x2 g23 = pk_gelu((f32x2){c4[tt][2], c4[tt][3]});
                unsigned u01 = cvt_pk_bf16(g01.x, g01.y);
                unsigned u23 = cvt_pk_bf16(g23.x, g23.y);
                actB[soff[tt * 4 + 0]] = (unsigned short)u01;
                actB[soff[tt * 4 + 1]] = (unsigned short)(u01 >> 16);
                actB[soff[tt * 4 + 2]] = (unsigned short)u23;
                actB[soff[tt * 4 + 3]] = (unsigned short)(u23 >> 16);
            }
        }
        wave_fence();

        // ---- L2 + fused L3: 8 MFMAs, tile-sum in regs, 4-shfl row reduce ----
        float sum0, sum1, sum2, sum3;
        {
            bf16x8 a0 = *prB0, a1 = *prB1;
            f32x4 c4[4];
            #pragma unroll
            for (int tt = 0; tt < 4; ++tt) {
                c4[tt] = (f32x4){bias2[tt], bias2[tt], bias2[tt], bias2[tt]};
                c4[tt] = __builtin_amdgcn_mfma_f32_16x16x32_bf16(a0, w2fa[tt], c4[tt], 0, 0, 0);
                c4[tt] = __builtin_amdgcn_mfma_f32_16x16x32_bf16(a1, w2fb[tt], c4[tt], 0, 0, 0);
            }
            float p0 = 0.0f, p1 = 0.0f, p2 = 0.0f, p3 = 0.0f;
            #pragma unroll
            for (int tt = 0; tt < 4; ++tt) {
                f32x2 g01 = pk_gelu((f32x2){c4[tt][0], c4[tt][1]});
                f32x2 g23 = pk_gelu((f32x2){c4[tt][2], c4[tt][3]});
                p0 += w3c[tt] * g01.x;
                p1 += w3c[tt] * g01.y;
                p2 += w3c[tt] * g23.x;
                p3 += w3c[tt] * g23.y;
            }
            p0 += __shfl_xor(p0, 1); p0 += __shfl_xor(p0, 2);
            p0 += __shfl_xor(p0, 4); p0 += __shfl_xor(p0, 8);
            p1 += __shfl_xor(p1, 1); p1 += __shfl_xor(p1, 2);
            p1 += __shfl_xor(p1, 4); p1 += __shfl_xor(p1, 8);
            p2 += __shfl_xor(p2, 1); p2 += __shfl_xor(p2, 2);
            p2 += __shfl_xor(p2, 4); p2 += __shfl_xor(p2, 8);
            p3 += __shfl_xor(p3, 1); p3 += __shfl_xor(p3, 2);
            p3 += __shfl_xor(p3, 4); p3 += __shfl_xor(p3, 8);
            sum0 = p0; sum1 = p1; sum2 = p2; sum3 = p3;
        }

        // ---- update + publish + store (lanes 0,16,32,48; rows row0+j) ----
        if (upd) {
            float sums[4] = {sum0, sum1, sum2, sum3};
            #pragma unroll
            for (int j = 0; j < 4; ++j) {
                float ns = st_reg[j] + r * (sums[j] + b3v);
                ns = fminf(1.0f, fmaxf(0.0f, ns));
                st_reg[j] = ns;
                if (t < NT - 1) {
                    u64t u = ((u64t)(unsigned)t << 32) |
                             (u64t)(unsigned)__builtin_bit_cast(unsigned, ns);
                    sys_store_u64(hpub + (size_t)((t & 3) * 16) + j, u);
                }
                orow[(size_t)t * NX + c0 + row0 + j] = ns;
                st_s[32 + row0 + j] = ns;
            }
        }
        wave_fence();   // center writes ordered before next iter's ballots
    }
}

extern "C" void kernel_launch(void* const* d_in, const int* in_sizes, int n_in,
                              void* d_out, int out_size, void* d_ws, size_t ws_size,
                              hipStream_t stream) {
    const float* grid = (const float*)d_in[0];
    const float* dtp  = (const float*)d_in[1];
    const float* W0   = (const float*)d_in[2];
    const float* b0   = (const float*)d_in[3];
    const float* W1   = (const float*)d_in[4];
    const float* b1   = (const float*)d_in[5];
    const float* W2   = (const float*)d_in[6];
    const float* b2   = (const float*)d_in[7];
    const float* W3   = (const float*)d_in[8];
    const float* b3   = (const float*)d_in[9];
    float* outp = (float*)d_out;

    u64t* halo = (u64t*)d_ws;                     // NBLK * 64 u64 (512 KB)

    // zero the whole mailbox each launch (stale embedded tags across replays)
    hipMemsetAsync(d_ws, 0, (size_t)NBLK * 64 * sizeof(u64t), stream);

    void* args[] = {(void*)&grid, (void*)&dtp, (void*)&W0, (void*)&b0,
                    (void*)&W1, (void*)&b1, (void*)&W2, (void*)&b2,
                    (void*)&W3, (void*)&b3, (void*)&outp, (void*)&halo};

    // Coop launch if occupancy allows >=4 single-wave blocks/CU (it will:
    // ~6.5KB LDS, 64 thr). Fallback: plain launch — all 1024 blocks fit
    // simultaneously, so mailbox spins remain live.
    int maxb = 0;
    hipError_t qe = hipOccupancyMaxActiveBlocksPerMultiprocessor(
        &maxb, (const void*)nfv_kernel, 64, 0);
    if (qe == hipSuccess && maxb >= 4) {
        hipLaunchCooperativeKernel((const void*)nfv_kernel,
                                   dim3(NBLK), dim3(64), args, 0, stream);
    } else {
        hipLaunchKernelGGL(nfv_kernel, dim3(NBLK), dim3(64), 0, stream,
                           grid, dtp, W0, b0, W1, b1, W2, b2, W3, b3,
                           outp, halo);
    }
}

// Round 20
// 185.822 us; speedup vs baseline: 1.0768x; 1.0768x over previous
//
#include <hip/hip_runtime.h>

#define NX 1024
#define NT 64
#define NBATCH 16
#define BPB 64           // blocks per batch chain (16 cells each)
#define NBLK (NBATCH * BPB)   // 1024 = 256 CUs x 4 blocks
#define DXC 0.02f
#define INV_SIG 20.0f
#define BIGF 1.0e6f

typedef __attribute__((ext_vector_type(8))) short bf16x8;
typedef __attribute__((ext_vector_type(4))) float f32x4;
typedef __attribute__((ext_vector_type(2))) float f32x2;
typedef unsigned long long u64t;

// round-to-nearest-even f32 -> bf16
__device__ __forceinline__ unsigned short f2bf(float x) {
    unsigned u = __builtin_bit_cast(unsigned, x);
    u += 0x7FFFu + ((u >> 16) & 1u);
    return (unsigned short)(u >> 16);
}
__device__ __forceinline__ float bf2f(unsigned short h) {
    return __builtin_bit_cast(float, (unsigned)h << 16);
}
// HW packed f32x2 -> bf16x2 (lo = src0, hi = src1) — proven r9-r18
__device__ __forceinline__ unsigned cvt_pk_bf16(float lo, float hi) {
    unsigned r;
    asm("v_cvt_pk_bf16_f32 %0, %1, %2" : "=v"(r) : "v"(lo), "v"(hi));
    return r;
}
__device__ __forceinline__ float hw_exp2(float v) {
    float e;
    asm("v_exp_f32 %0, %1" : "=v"(e) : "v"(v));
    return e;
}

// 2-wide tanh-form GELU in native vector C (no VOP3P asm — r17 lesson).
//   gelu(x) = x - x / (1 + exp2( x * (0.1029456*x^2 + 2.3022654) ))
__device__ __forceinline__ f32x2 pk_gelu(f32x2 x) {
    f32x2 x2 = x * x;
    f32x2 v  = x * (x2 * 0.1029456f + 2.3022654f);
    f32x2 rc;
    rc.x = __builtin_amdgcn_rcpf(hw_exp2(v.x) + 1.0f);
    rc.y = __builtin_amdgcn_rcpf(hw_exp2(v.y) + 1.0f);
    return x - x * rc;
}

// SYSTEM-scope relaxed (L3 coherence point; no cache inv/wb) — cross-XCD safe.
__device__ __forceinline__ u64t sys_load_u64(const u64t* p) {
    return __hip_atomic_load(p, __ATOMIC_RELAXED, __HIP_MEMORY_SCOPE_SYSTEM);
}
__device__ __forceinline__ void sys_store_u64(u64t* p, u64t v) {
    __hip_atomic_store(p, v, __ATOMIC_RELAXED, __HIP_MEMORY_SCOPE_SYSTEM);
}

// XOR-swizzled [R][64] bf16 LDS layout: 16B chunk index XOR'd with row&7.
__device__ __forceinline__ int swz(int row, int k) {
    return (row << 6) + ((((k >> 3) ^ row) & 7) << 3) + (k & 7);
}

__global__ void __launch_bounds__(256, 4) nfv_kernel(
    const float* __restrict__ grid, const float* __restrict__ dtp,
    const float* __restrict__ W0, const float* __restrict__ b0,
    const float* __restrict__ W1, const float* __restrict__ b1,
    const float* __restrict__ W2, const float* __restrict__ b2,
    const float* __restrict__ W3, const float* __restrict__ b3,
    float* __restrict__ outp, u64t* __restrict__ halo)
{
    __shared__ float st_s[80];      // state strip, global [c0-32, c0+48)
    __shared__ __align__(16) unsigned short feat_s[16 * 64]; // bf16 features, swz
    __shared__ __align__(16) unsigned short actA[16 * 64];
    __shared__ __align__(16) unsigned short actB[16 * 64];
    __shared__ __align__(16) float part_s[16 * 20];          // [row][16 partials + pad]

    const int tid  = threadIdx.x;
    const int lane = tid & 63;
    const int wid  = tid >> 6;            // 0..3
    const int bid  = blockIdx.x;
    const int b    = bid >> 6;            // batch
    const int bb   = bid & 63;            // block within chain
    const int c0   = bb * 16;
    const float dtv = dtp[b];
    const float r   = dtv / DXC;
    const float b3v = b3[0];

    const float* grow = grid + (size_t)b * (NT * NX);
    float*       orow = outp + (size_t)b * (NT * NX);

    // fragment geometry: 4 waves = 1x4 tiles of 16x16 (M=16 cells, N=64 ch)
    const int l15 = lane & 15;
    const int kb0 = lane >> 4;                   // 16B-chunk idx: 0..3
    const int col = wid * 16 + l15;              // output channel (0..63)
    const int row0 = (lane >> 4) << 2;           // C rows: 0,4,8,12 (+j)
    const int arow = l15;                        // feat/act row (0..15)

    // ---- prologue: per-lane constant weight fragments (registers) ----
    // L0 refactor: W0[:,k]*s + W0[:,7+k]*(1-2s) = A_k*s + W0[:,7+k],
    //   A_k = W0[:,k]-2*W0[:,7+k]. Slot k: A_k (s_hi); slot 7+k: A_k (s_lo);
    //   slots 14..20: prox weights; 21: dt weight; 22..31: zero.
    bf16x8 w0f, w1fa, w1fb, w2fa, w2fb;
    {
        const int k0 = kb0 * 8;
        #pragma unroll
        for (int i = 0; i < 8; ++i) {
            int k = k0 + i;
            float wv;
            if (k < 7)       wv = W0[col * 22 + k] - 2.0f * W0[col * 22 + 7 + k];
            else if (k < 14) wv = W0[col * 22 + (k - 7)] - 2.0f * W0[col * 22 + k];
            else if (k < 22) wv = W0[col * 22 + k];
            else             wv = 0.0f;
            w0f[i]  = (short)f2bf(wv);
            w1fa[i] = (short)f2bf(W1[col * 64 + k0 + i]);
            w1fb[i] = (short)f2bf(W1[col * 64 + k0 + 32 + i]);
            w2fa[i] = (short)f2bf(W2[col * 64 + k0 + i]);
            w2fb[i] = (short)f2bf(W2[col * 64 + k0 + 32 + i]);
        }
    }
    float bias0 = b0[col];
    #pragma unroll
    for (int k = 7; k < 14; ++k) bias0 += W0[col * 22 + k];  // char constant fold
    const float bias1 = b1[col], bias2 = b2[col], w3c = W3[col];

    // ---- hoisted loop-invariant LDS addresses (named scalars, rule #20) ----
    const int aoffA = (arow << 6) + (((kb0    ) ^ arow) * 8 & 56);  // chunk kb0
    const int aoffB = (arow << 6) + ((((kb0+4) ^ arow) & 7) << 3);  // chunk kb0+4
    const bf16x8* const prF  = (const bf16x8*)(const void*)&feat_s[aoffA];
    const bf16x8* const prA0 = (const bf16x8*)(const void*)&actA[aoffA];
    const bf16x8* const prA1 = (const bf16x8*)(const void*)&actA[aoffB];
    const bf16x8* const prB0 = (const bf16x8*)(const void*)&actB[aoffA];
    const bf16x8* const prB1 = (const bf16x8*)(const void*)&actB[aoffB];
    unsigned short* const pwA0 = &actA[swz(row0    , col)];
    unsigned short* const pwA1 = &actA[swz(row0 + 1, col)];
    unsigned short* const pwA2 = &actA[swz(row0 + 2, col)];
    unsigned short* const pwA3 = &actA[swz(row0 + 3, col)];
    unsigned short* const pwB0 = &actB[swz(row0    , col)];
    unsigned short* const pwB1 = &actB[swz(row0 + 1, col)];
    unsigned short* const pwB2 = &actB[swz(row0 + 2, col)];
    unsigned short* const pwB3 = &actB[swz(row0 + 3, col)];
    const int poff = row0 * 20 + (wid << 2) + (l15 >> 2);   // part_s writer
    const bool pwrite = ((l15 & 3) == 0);

    // feature-phase constants
    const int fslot = wid * 2 + (lane >> 5);        // stencil slot 0..7
    const int frow  = lane & 15;
    const bool fact = (fslot < 7) && ((lane & 31) < 16);
    int fc = frow + 29 + fslot;                      // strip query cell
    if (bb == 0       && fc < 32) fc = 32;
    if (bb == BPB - 1 && fc > 47) fc = 47;
    const int foff0 = swz(frow, fslot);
    const int foff1 = swz(frow, 7 + fslot);
    const int foff2 = swz(frow, 14 + fslot);

    // halo-poll constants (wave1 in E-window)
    int hg = (lane < 32) ? (c0 - 32 + lane) : (c0 - 16 + lane);
    hg = hg < 0 ? 0 : (hg > NX - 1 ? NX - 1 : hg);
    const u64t* const hbase = &halo[(size_t)(b * BPB + (hg >> 4)) * 64 + (hg & 15)];
    const int hdst = (lane < 32) ? lane : lane + 16;

    // update-phase constants (wave0, lanes 0..15)
    const f32x4* const pru = (const f32x4*)(const void*)&part_s[l15 * 20];
    u64t* const hpub = &halo[(size_t)bid * 64 + l15];
    float* const ocell = orow + c0 + l15;

    ((unsigned*)feat_s)[tid]       = 0;    // zero all 1024 bf16 entries
    ((unsigned*)feat_s)[tid + 256] = 0;    // (pad K slots stay 0 forever)
    if (tid < 16) {
        orow[c0 + tid] = grow[c0 + tid];   // t = 0 output
        feat_s[swz(tid, 21)] = f2bf(dtv);  // dt slot: constant, write once
    }
    if (tid < 80) {                        // initial strip (row 0), edge-clamped
        int ga = c0 - 32 + tid;
        ga = ga < 0 ? 0 : (ga > NX - 1 ? NX - 1 : ga);
        st_s[tid] = grow[ga];
    }
    __syncthreads();   // prologue complete; strip holds row 0

    // ---- start-skew: de-correlate co-resident blocks ----
    // CU hosts bids {i, i+256, i+512, i+768} = batches {b, b+4, b+8, b+12};
    // (b>>2)&3 is distinct across them. Chains are batch-local (mailbox,
    // orow) so the offset persists all 63 steps; stalls then interleave
    // instead of convoying. Cost: <=3.6us tail. Numerics untouched.
    {
        const int skew = (b >> 2) & 3;
        for (int i = 0; i < skew * 3; ++i) __builtin_amdgcn_s_sleep(15);
    }

    for (int t = 1; t < NT; ++t) {
        // ---- all waves: ballot prox + features (st_s = row t-1) ----
        {
            // shock ballots over strip pairs p=0..78 (pair p: cells p,p+1)
            bool q0 = st_s[lane + 1] > st_s[lane];               // pairs 0..63
            bool q1 = (lane < 15) && (st_s[65 + lane] > st_s[64 + lane]);
            u64t m0 = __ballot(q0);
            u64t m1 = __ballot(q1);
            if (fact) {
                const int c = fc;
                float dL = BIGF, dR = BIGF;
                u64t sello = m0 & (((u64t)1 << c) - 1); // pairs <= c-1
                if (sello) dL = (float)(c - (63 - __builtin_clzll(sello))) - 0.5f;
                u64t r0 = m0 >> c;                      // pairs >= c
                if (r0)      dR = (float)__builtin_ctzll(r0) + 0.5f;
                else if (m1) dR = (float)(64 - c + __builtin_ctzll(m1)) + 0.5f;
                float d = fminf(dL, dR);                // in cell units
                float prox = hw_exp2(d * -0.5770780f);  // exp(-0.4 d)

                float sv = st_s[c];
                unsigned short shi = f2bf(sv);
                unsigned short slo = f2bf(sv - bf2f(shi));  // double-bf16 state
                feat_s[foff0] = shi;
                feat_s[foff1] = slo;
                feat_s[foff2] = f2bf(prox);
            }
        }
        __syncthreads();   // B: features ready

        // ---- L0 (1x MFMA bf16, K=32): feat x W0'^T -> actA ----
        {
            f32x4 c4 = {bias0, bias0, bias0, bias0};   // bias folded into C-init
            c4 = __builtin_amdgcn_mfma_f32_16x16x32_bf16(*prF, w0f, c4, 0, 0, 0);
            f32x2 g01 = pk_gelu((f32x2){c4[0], c4[1]});
            f32x2 g23 = pk_gelu((f32x2){c4[2], c4[3]});
            unsigned u01 = cvt_pk_bf16(g01.x, g01.y);
            unsigned u23 = cvt_pk_bf16(g23.x, g23.y);
            *pwA0 = (unsigned short)u01;
            *pwA1 = (unsigned short)(u01 >> 16);
            *pwA2 = (unsigned short)u23;
            *pwA3 = (unsigned short)(u23 >> 16);
        }
        __syncthreads();   // C: actA ready

        // ---- L1 (MFMA bf16, K=64): actA x W1^T -> actB ----
        {
            f32x4 c4 = {bias1, bias1, bias1, bias1};
            c4 = __builtin_amdgcn_mfma_f32_16x16x32_bf16(*prA0, w1fa, c4, 0, 0, 0);
            c4 = __builtin_amdgcn_mfma_f32_16x16x32_bf16(*prA1, w1fb, c4, 0, 0, 0);
            f32x2 g01 = pk_gelu((f32x2){c4[0], c4[1]});
            f32x2 g23 = pk_gelu((f32x2){c4[2], c4[3]});
            unsigned u01 = cvt_pk_bf16(g01.x, g01.y);
            unsigned u23 = cvt_pk_bf16(g23.x, g23.y);
            *pwB0 = (unsigned short)u01;
            *pwB1 = (unsigned short)(u01 >> 16);
            *pwB2 = (unsigned short)u23;
            *pwB3 = (unsigned short)(u23 >> 16);
        }
        __syncthreads();   // D: actB ready

        // ---- L2 (MFMA bf16) + fused L3 partial (2-stage shfl -> 16/row) ----
        {
            f32x4 c4 = {bias2, bias2, bias2, bias2};
            c4 = __builtin_amdgcn_mfma_f32_16x16x32_bf16(*prB0, w2fa, c4, 0, 0, 0);
            c4 = __builtin_amdgcn_mfma_f32_16x16x32_bf16(*prB1, w2fb, c4, 0, 0, 0);
            f32x2 g01 = pk_gelu((f32x2){c4[0], c4[1]});
            f32x2 g23 = pk_gelu((f32x2){c4[2], c4[3]});
            float pj0 = w3c * g01.x, pj1 = w3c * g01.y;
            float pj2 = w3c * g23.x, pj3 = w3c * g23.y;
            {
                float p = pj0;
                p += __shfl_xor(p, 1); p += __shfl_xor(p, 2);
                if (pwrite) part_s[poff] = p;
            }
            {
                float p = pj1;
                p += __shfl_xor(p, 1); p += __shfl_xor(p, 2);
                if (pwrite) part_s[poff + 20] = p;
            }
            {
                float p = pj2;
                p += __shfl_xor(p, 1); p += __shfl_xor(p, 2);
                if (pwrite) part_s[poff + 40] = p;
            }
            {
                float p = pj3;
                p += __shfl_xor(p, 1); p += __shfl_xor(p, 2);
                if (pwrite) part_s[poff + 60] = p;
            }
        }
        __syncthreads();   // E: partials ready

        // ---- E->A window: wave0 update+publish  ||  wave1 poll row t halo ----
        // Disjoint st_s regions: wave0 writes [32..47]; wave1 writes [0..31],
        // [64..79]. Edge blocks' clamped lanes self-poll the word wave0 is
        // publishing in this same window — wave0 never waits on wave1 (live).
        if (wid == 0 && lane < 16) {
            f32x4 s4 = pru[0] + pru[1] + pru[2] + pru[3];
            float sum = s4[0] + s4[1] + s4[2] + s4[3];
            float ns = st_s[32 + l15] + r * (sum + b3v);
            ns = fminf(1.0f, fmaxf(0.0f, ns));
            if (t < NT - 1) {
                u64t u = ((u64t)(unsigned)t << 32) |
                         (u64t)(unsigned)__builtin_bit_cast(unsigned, ns);
                sys_store_u64(hpub + (size_t)((t & 3) * 16), u);
            }
            ocell[(size_t)t * NX] = ns;
            st_s[32 + l15] = ns;
        } else if (wid == 1 && t < NT - 1) {
            // fill strip halo with row t from neighbors (fused data+tag/lane);
            // consumed by next iteration's feature phase after barrier A
            const unsigned need = (unsigned)t;
            const u64t* src = hbase + (size_t)((t & 3) * 16);
            u64t u;
            do { u = sys_load_u64(src); } while ((unsigned)(u >> 32) < need);
            st_s[hdst] = __builtin_bit_cast(float, (unsigned)u);
        }
        __syncthreads();   // A: strip now holds row t (+ halo); next iteration
    }
}

extern "C" void kernel_launch(void* const* d_in, const int* in_sizes, int n_in,
                              void* d_out, int out_size, void* d_ws, size_t ws_size,
                              hipStream_t stream) {
    const float* grid = (const float*)d_in[0];
    const float* dtp  = (const float*)d_in[1];
    const float* W0   = (const float*)d_in[2];
    const float* b0   = (const float*)d_in[3];
    const float* W1   = (const float*)d_in[4];
    const float* b1   = (const float*)d_in[5];
    const float* W2   = (const float*)d_in[6];
    const float* b2   = (const float*)d_in[7];
    const float* W3   = (const float*)d_in[8];
    const float* b3   = (const float*)d_in[9];
    float* outp = (float*)d_out;

    u64t* halo = (u64t*)d_ws;                     // NBLK * 64 u64 (512 KB)

    // zero the whole mailbox each launch: tags embedded in data words must
    // not leak across graph replays (stale tag >= need hands out old rows)
    hipMemsetAsync(d_ws, 0, (size_t)NBLK * 64 * sizeof(u64t), stream);

    void* args[] = {(void*)&grid, (void*)&dtp, (void*)&W0, (void*)&b0,
                    (void*)&W1, (void*)&b1, (void*)&W2, (void*)&b2,
                    (void*)&W3, (void*)&b3, (void*)&outp, (void*)&halo};

    // Deterministic launch-mode choice (query enqueues nothing; capture-safe).
    // Coop launch caps grid at occupancy*256; need >=4 blocks/CU for 1024.
    // Fallback plain launch: all 1024 blocks fit simultaneously (8KB LDS,
    // 256 thr, VGPR bounded) -> spins stay live.
    int maxb = 0;
    hipError_t qe = hipOccupancyMaxActiveBlocksPerMultiprocessor(
        &maxb, (const void*)nfv_kernel, 256, 0);
    if (qe == hipSuccess && maxb >= 4) {
        hipLaunchCooperativeKernel((const void*)nfv_kernel,
                                   dim3(NBLK), dim3(256), args, 0, stream);
    } else {
        hipLaunchKernelGGL(nfv_kernel, dim3(NBLK), dim3(256), 0, stream,
                           grid, dtp, W0, b0, W1, b1, W2, b2, W3, b3,
                           outp, halo);
    }
}

// Round 21
// 182.717 us; speedup vs baseline: 1.0951x; 1.0170x over previous
//
#include <hip/hip_runtime.h>

#define NX 1024
#define NT 64
#define NBATCH 16
#define BPB 64           // blocks per batch chain (16 cells each)
#define NBLK (NBATCH * BPB)   // 1024 = 256 CUs x 4 blocks
#define DXC 0.02f
#define INV_SIG 20.0f
#define BIGF 1.0e6f

typedef __attribute__((ext_vector_type(8))) short bf16x8;
typedef __attribute__((ext_vector_type(4))) float f32x4;
typedef __attribute__((ext_vector_type(2))) float f32x2;
typedef unsigned long long u64t;

// round-to-nearest-even f32 -> bf16
__device__ __forceinline__ unsigned short f2bf(float x) {
    unsigned u = __builtin_bit_cast(unsigned, x);
    u += 0x7FFFu + ((u >> 16) & 1u);
    return (unsigned short)(u >> 16);
}
__device__ __forceinline__ float bf2f(unsigned short h) {
    return __builtin_bit_cast(float, (unsigned)h << 16);
}
// HW packed f32x2 -> bf16x2 (lo = src0, hi = src1) — proven r9-r20
__device__ __forceinline__ unsigned cvt_pk_bf16(float lo, float hi) {
    unsigned r;
    asm("v_cvt_pk_bf16_f32 %0, %1, %2" : "=v"(r) : "v"(lo), "v"(hi));
    return r;
}
__device__ __forceinline__ float hw_exp2(float v) {
    float e;
    asm("v_exp_f32 %0, %1" : "=v"(e) : "v"(v));
    return e;
}

// 2-wide tanh-form GELU in native vector C (no VOP3P asm — r17 lesson).
//   gelu(x) = x - x / (1 + exp2( x * (0.1029456*x^2 + 2.3022654) ))
__device__ __forceinline__ f32x2 pk_gelu(f32x2 x) {
    f32x2 x2 = x * x;
    f32x2 v  = x * (x2 * 0.1029456f + 2.3022654f);
    f32x2 rc;
    rc.x = __builtin_amdgcn_rcpf(hw_exp2(v.x) + 1.0f);
    rc.y = __builtin_amdgcn_rcpf(hw_exp2(v.y) + 1.0f);
    return x - x * rc;
}

// SYSTEM-scope relaxed (L3 coherence point; no cache inv/wb) — cross-XCD safe.
__device__ __forceinline__ u64t sys_load_u64(const u64t* p) {
    return __hip_atomic_load(p, __ATOMIC_RELAXED, __HIP_MEMORY_SCOPE_SYSTEM);
}
__device__ __forceinline__ void sys_store_u64(u64t* p, u64t v) {
    __hip_atomic_store(p, v, __ATOMIC_RELAXED, __HIP_MEMORY_SCOPE_SYSTEM);
}

// Raw block barrier WITHOUT the vmcnt(0) drain __syncthreads emits.
// LDS ordering preserved (lgkmcnt(0) before s_barrier); vmem stores
// (orow to HBM, mailbox publish to L3) drain lazily — nothing in-block
// depends on them, and the mailbox word is single-8B-atomic (tag fused
// with data), so consumers need no store-order guarantee beyond that.
__device__ __forceinline__ void lds_barrier() {
    asm volatile("s_waitcnt lgkmcnt(0)\n\ts_barrier" ::: "memory");
}

// XOR-swizzled [R][64] bf16 LDS layout: 16B chunk index XOR'd with row&7.
__device__ __forceinline__ int swz(int row, int k) {
    return (row << 6) + ((((k >> 3) ^ row) & 7) << 3) + (k & 7);
}

__global__ void __launch_bounds__(256, 4) nfv_kernel(
    const float* __restrict__ grid, const float* __restrict__ dtp,
    const float* __restrict__ W0, const float* __restrict__ b0,
    const float* __restrict__ W1, const float* __restrict__ b1,
    const float* __restrict__ W2, const float* __restrict__ b2,
    const float* __restrict__ W3, const float* __restrict__ b3,
    float* __restrict__ outp, u64t* __restrict__ halo)
{
    __shared__ float st_s[80];      // state strip, global [c0-32, c0+48)
    __shared__ __align__(16) unsigned short feat_s[16 * 64]; // bf16 features, swz
    __shared__ __align__(16) unsigned short actA[16 * 64];
    __shared__ __align__(16) unsigned short actB[16 * 64];
    __shared__ __align__(16) float part_s[16 * 20];          // [row][16 partials + pad]

    const int tid  = threadIdx.x;
    const int lane = tid & 63;
    const int wid  = tid >> 6;            // 0..3
    const int bid  = blockIdx.x;
    const int b    = bid >> 6;            // batch
    const int bb   = bid & 63;            // block within chain
    const int c0   = bb * 16;
    const float dtv = dtp[b];
    const float r   = dtv / DXC;
    const float b3v = b3[0];

    const float* grow = grid + (size_t)b * (NT * NX);
    float*       orow = outp + (size_t)b * (NT * NX);

    // fragment geometry: 4 waves = 1x4 tiles of 16x16 (M=16 cells, N=64 ch)
    const int l15 = lane & 15;
    const int kb0 = lane >> 4;                   // 16B-chunk idx: 0..3
    const int col = wid * 16 + l15;              // output channel (0..63)
    const int row0 = (lane >> 4) << 2;           // C rows: 0,4,8,12 (+j)
    const int arow = l15;                        // feat/act row (0..15)

    // ---- prologue: per-lane constant weight fragments (registers) ----
    // L0 refactor: W0[:,k]*s + W0[:,7+k]*(1-2s) = A_k*s + W0[:,7+k],
    //   A_k = W0[:,k]-2*W0[:,7+k]. Slot k: A_k (s_hi); slot 7+k: A_k (s_lo);
    //   slots 14..20: prox weights; 21: dt weight; 22..31: zero.
    bf16x8 w0f, w1fa, w1fb, w2fa, w2fb;
    {
        const int k0 = kb0 * 8;
        #pragma unroll
        for (int i = 0; i < 8; ++i) {
            int k = k0 + i;
            float wv;
            if (k < 7)       wv = W0[col * 22 + k] - 2.0f * W0[col * 22 + 7 + k];
            else if (k < 14) wv = W0[col * 22 + (k - 7)] - 2.0f * W0[col * 22 + k];
            else if (k < 22) wv = W0[col * 22 + k];
            else             wv = 0.0f;
            w0f[i]  = (short)f2bf(wv);
            w1fa[i] = (short)f2bf(W1[col * 64 + k0 + i]);
            w1fb[i] = (short)f2bf(W1[col * 64 + k0 + 32 + i]);
            w2fa[i] = (short)f2bf(W2[col * 64 + k0 + i]);
            w2fb[i] = (short)f2bf(W2[col * 64 + k0 + 32 + i]);
        }
    }
    float bias0 = b0[col];
    #pragma unroll
    for (int k = 7; k < 14; ++k) bias0 += W0[col * 22 + k];  // char constant fold
    const float bias1 = b1[col], bias2 = b2[col], w3c = W3[col];

    // ---- hoisted loop-invariant LDS addresses (named scalars, rule #20) ----
    const int aoffA = (arow << 6) + (((kb0    ) ^ arow) * 8 & 56);  // chunk kb0
    const int aoffB = (arow << 6) + ((((kb0+4) ^ arow) & 7) << 3);  // chunk kb0+4
    const bf16x8* const prF  = (const bf16x8*)(const void*)&feat_s[aoffA];
    const bf16x8* const prA0 = (const bf16x8*)(const void*)&actA[aoffA];
    const bf16x8* const prA1 = (const bf16x8*)(const void*)&actA[aoffB];
    const bf16x8* const prB0 = (const bf16x8*)(const void*)&actB[aoffA];
    const bf16x8* const prB1 = (const bf16x8*)(const void*)&actB[aoffB];
    unsigned short* const pwA0 = &actA[swz(row0    , col)];
    unsigned short* const pwA1 = &actA[swz(row0 + 1, col)];
    unsigned short* const pwA2 = &actA[swz(row0 + 2, col)];
    unsigned short* const pwA3 = &actA[swz(row0 + 3, col)];
    unsigned short* const pwB0 = &actB[swz(row0    , col)];
    unsigned short* const pwB1 = &actB[swz(row0 + 1, col)];
    unsigned short* const pwB2 = &actB[swz(row0 + 2, col)];
    unsigned short* const pwB3 = &actB[swz(row0 + 3, col)];
    const int poff = row0 * 20 + (wid << 2) + (l15 >> 2);   // part_s writer
    const bool pwrite = ((l15 & 3) == 0);

    // feature-phase constants
    const int fslot = wid * 2 + (lane >> 5);        // stencil slot 0..7
    const int frow  = lane & 15;
    const bool fact = (fslot < 7) && ((lane & 31) < 16);
    int fc = frow + 29 + fslot;                      // strip query cell
    if (bb == 0       && fc < 32) fc = 32;
    if (bb == BPB - 1 && fc > 47) fc = 47;
    const int foff0 = swz(frow, fslot);
    const int foff1 = swz(frow, 7 + fslot);
    const int foff2 = swz(frow, 14 + fslot);

    // halo-poll constants (wave1 in E-window)
    int hg = (lane < 32) ? (c0 - 32 + lane) : (c0 - 16 + lane);
    hg = hg < 0 ? 0 : (hg > NX - 1 ? NX - 1 : hg);
    const u64t* const hbase = &halo[(size_t)(b * BPB + (hg >> 4)) * 64 + (hg & 15)];
    const int hdst = (lane < 32) ? lane : lane + 16;

    // update-phase constants (wave0, lanes 0..15)
    const f32x4* const pru = (const f32x4*)(const void*)&part_s[l15 * 20];
    u64t* const hpub = &halo[(size_t)bid * 64 + l15];
    float* const ocell = orow + c0 + l15;

    ((unsigned*)feat_s)[tid]       = 0;    // zero all 1024 bf16 entries
    ((unsigned*)feat_s)[tid + 256] = 0;    // (pad K slots stay 0 forever)
    if (tid < 16) {
        orow[c0 + tid] = grow[c0 + tid];   // t = 0 output
        feat_s[swz(tid, 21)] = f2bf(dtv);  // dt slot: constant, write once
    }
    if (tid < 80) {                        // initial strip (row 0), edge-clamped
        int ga = c0 - 32 + tid;
        ga = ga < 0 ? 0 : (ga > NX - 1 ? NX - 1 : ga);
        st_s[tid] = grow[ga];
    }
    __syncthreads();   // prologue: full barrier once (vmem loads must land)

    for (int t = 1; t < NT; ++t) {
        // ---- all waves: ballot prox + features (st_s = row t-1) ----
        {
            // shock ballots over strip pairs p=0..78 (pair p: cells p,p+1)
            bool q0 = st_s[lane + 1] > st_s[lane];               // pairs 0..63
            bool q1 = (lane < 15) && (st_s[65 + lane] > st_s[64 + lane]);
            u64t m0 = __ballot(q0);
            u64t m1 = __ballot(q1);
            if (fact) {
                const int c = fc;
                float dL = BIGF, dR = BIGF;
                u64t sello = m0 & (((u64t)1 << c) - 1); // pairs <= c-1
                if (sello) dL = (float)(c - (63 - __builtin_clzll(sello))) - 0.5f;
                u64t r0 = m0 >> c;                      // pairs >= c
                if (r0)      dR = (float)__builtin_ctzll(r0) + 0.5f;
                else if (m1) dR = (float)(64 - c + __builtin_ctzll(m1)) + 0.5f;
                float d = fminf(dL, dR);                // in cell units
                float prox = hw_exp2(d * -0.5770780f);  // exp(-0.4 d)

                float sv = st_s[c];
                unsigned short shi = f2bf(sv);
                unsigned short slo = f2bf(sv - bf2f(shi));  // double-bf16 state
                feat_s[foff0] = shi;
                feat_s[foff1] = slo;
                feat_s[foff2] = f2bf(prox);
            }
        }
        lds_barrier();   // B: features ready (LDS-only ordering needed)

        // ---- L0 (1x MFMA bf16, K=32): feat x W0'^T -> actA ----
        {
            f32x4 c4 = {bias0, bias0, bias0, bias0};   // bias folded into C-init
            c4 = __builtin_amdgcn_mfma_f32_16x16x32_bf16(*prF, w0f, c4, 0, 0, 0);
            f32x2 g01 = pk_gelu((f32x2){c4[0], c4[1]});
            f32x2 g23 = pk_gelu((f32x2){c4[2], c4[3]});
            unsigned u01 = cvt_pk_bf16(g01.x, g01.y);
            unsigned u23 = cvt_pk_bf16(g23.x, g23.y);
            *pwA0 = (unsigned short)u01;
            *pwA1 = (unsigned short)(u01 >> 16);
            *pwA2 = (unsigned short)u23;
            *pwA3 = (unsigned short)(u23 >> 16);
        }
        lds_barrier();   // C: actA ready

        // ---- L1 (MFMA bf16, K=64): actA x W1^T -> actB ----
        {
            f32x4 c4 = {bias1, bias1, bias1, bias1};
            c4 = __builtin_amdgcn_mfma_f32_16x16x32_bf16(*prA0, w1fa, c4, 0, 0, 0);
            c4 = __builtin_amdgcn_mfma_f32_16x16x32_bf16(*prA1, w1fb, c4, 0, 0, 0);
            f32x2 g01 = pk_gelu((f32x2){c4[0], c4[1]});
            f32x2 g23 = pk_gelu((f32x2){c4[2], c4[3]});
            unsigned u01 = cvt_pk_bf16(g01.x, g01.y);
            unsigned u23 = cvt_pk_bf16(g23.x, g23.y);
            *pwB0 = (unsigned short)u01;
            *pwB1 = (unsigned short)(u01 >> 16);
            *pwB2 = (unsigned short)u23;
            *pwB3 = (unsigned short)(u23 >> 16);
        }
        lds_barrier();   // D: actB ready

        // ---- L2 (MFMA bf16) + fused L3 partial (2-stage shfl -> 16/row) ----
        {
            f32x4 c4 = {bias2, bias2, bias2, bias2};
            c4 = __builtin_amdgcn_mfma_f32_16x16x32_bf16(*prB0, w2fa, c4, 0, 0, 0);
            c4 = __builtin_amdgcn_mfma_f32_16x16x32_bf16(*prB1, w2fb, c4, 0, 0, 0);
            f32x2 g01 = pk_gelu((f32x2){c4[0], c4[1]});
            f32x2 g23 = pk_gelu((f32x2){c4[2], c4[3]});
            float pj0 = w3c * g01.x, pj1 = w3c * g01.y;
            float pj2 = w3c * g23.x, pj3 = w3c * g23.y;
            {
                float p = pj0;
                p += __shfl_xor(p, 1); p += __shfl_xor(p, 2);
                if (pwrite) part_s[poff] = p;
            }
            {
                float p = pj1;
                p += __shfl_xor(p, 1); p += __shfl_xor(p, 2);
                if (pwrite) part_s[poff + 20] = p;
            }
            {
                float p = pj2;
                p += __shfl_xor(p, 1); p += __shfl_xor(p, 2);
                if (pwrite) part_s[poff + 40] = p;
            }
            {
                float p = pj3;
                p += __shfl_xor(p, 1); p += __shfl_xor(p, 2);
                if (pwrite) part_s[poff + 60] = p;
            }
        }
        lds_barrier();   // E: partials ready

        // ---- E->A window: wave0 update+publish  ||  wave1 poll row t halo ----
        // Disjoint st_s regions: wave0 writes [32..47]; wave1 writes [0..31],
        // [64..79]. Edge blocks' clamped lanes self-poll the word wave0 is
        // publishing in this same window — wave0 never waits on wave1 (live).
        if (wid == 0 && lane < 16) {
            f32x4 s4 = pru[0] + pru[1] + pru[2] + pru[3];
            float sum = s4[0] + s4[1] + s4[2] + s4[3];
            float ns = st_s[32 + l15] + r * (sum + b3v);
            ns = fminf(1.0f, fmaxf(0.0f, ns));
            if (t < NT - 1) {
                u64t u = ((u64t)(unsigned)t << 32) |
                         (u64t)(unsigned)__builtin_bit_cast(unsigned, ns);
                sys_store_u64(hpub + (size_t)((t & 3) * 16), u);
            }
            ocell[(size_t)t * NX] = ns;
            st_s[32 + l15] = ns;
        } else if (wid == 1 && t < NT - 1) {
            // fill strip halo with row t from neighbors (fused data+tag/lane);
            // consumed by next iteration's feature phase after barrier A
            const unsigned need = (unsigned)t;
            const u64t* src = hbase + (size_t)((t & 3) * 16);
            u64t u;
            do { u = sys_load_u64(src); } while ((unsigned)(u >> 32) < need);
            st_s[hdst] = __builtin_bit_cast(float, (unsigned)u);
        }
        lds_barrier();   // A: strip holds row t — no vmcnt drain (the win)
    }
}

extern "C" void kernel_launch(void* const* d_in, const int* in_sizes, int n_in,
                              void* d_out, int out_size, void* d_ws, size_t ws_size,
                              hipStream_t stream) {
    const float* grid = (const float*)d_in[0];
    const float* dtp  = (const float*)d_in[1];
    const float* W0   = (const float*)d_in[2];
    const float* b0   = (const float*)d_in[3];
    const float* W1   = (const float*)d_in[4];
    const float* b1   = (const float*)d_in[5];
    const float* W2   = (const float*)d_in[6];
    const float* b2   = (const float*)d_in[7];
    const float* W3   = (const float*)d_in[8];
    const float* b3   = (const float*)d_in[9];
    float* outp = (float*)d_out;

    u64t* halo = (u64t*)d_ws;                     // NBLK * 64 u64 (512 KB)

    // zero the whole mailbox each launch: tags embedded in data words must
    // not leak across graph replays (stale tag >= need hands out old rows)
    hipMemsetAsync(d_ws, 0, (size_t)NBLK * 64 * sizeof(u64t), stream);

    void* args[] = {(void*)&grid, (void*)&dtp, (void*)&W0, (void*)&b0,
                    (void*)&W1, (void*)&b1, (void*)&W2, (void*)&b2,
                    (void*)&W3, (void*)&b3, (void*)&outp, (void*)&halo};

    // Deterministic launch-mode choice (query enqueues nothing; capture-safe).
    // Coop launch caps grid at occupancy*256; need >=4 blocks/CU for 1024.
    // Fallback plain launch: all 1024 blocks fit simultaneously (8KB LDS,
    // 256 thr, VGPR bounded) -> spins stay live.
    int maxb = 0;
    hipError_t qe = hipOccupancyMaxActiveBlocksPerMultiprocessor(
        &maxb, (const void*)nfv_kernel, 256, 0);
    if (qe == hipSuccess && maxb >= 4) {
        hipLaunchCooperativeKernel((const void*)nfv_kernel,
                                   dim3(NBLK), dim3(256), args, 0, stream);
    } else {
        hipLaunchKernelGGL(nfv_kernel, dim3(NBLK), dim3(256), 0, stream,
                           grid, dtp, W0, b0, W1, b1, W2, b2, W3, b3,
                           outp, halo);
    }
}